// Round 1
// baseline (99.647 us; speedup 1.0000x reference)
//
#include <hip/hip_runtime.h>
#include <math.h>

#define NPERSEG 1024
#define STEP    256
#define NWIN    61
#define SEQ     16384
#define BATCH   1024

// Kernel 1: effective per-position weights.
// wc[s] = sum over windows w covering s of cos(2*pi*freqs[p]), p = s - 256*w
// ws[s] = sum of -sin(...). Each position is covered by <= 4 windows.
__global__ void welch_weights_kernel(const float* __restrict__ freqs,
                                     float* __restrict__ wc,
                                     float* __restrict__ ws) {
    int s = blockIdx.x * blockDim.x + threadIdx.x;
    if (s >= SEQ) return;
    int p0    = s & (STEP - 1);   // s mod 256
    int wbase = s >> 8;           // s / 256
    float c = 0.f, sn = 0.f;
    #pragma unroll
    for (int k = 0; k < 4; ++k) {
        int w = wbase - k;
        if (w >= 0 && w < NWIN) {
            int p = p0 + STEP * k;          // always < 1024
            float a = 6.2831853071795864769f * freqs[p];
            float sv, cv;
            sincosf(a, &sv, &cv);           // accurate variant; cost negligible
            c  += cv;
            sn -= sv;
        }
    }
    wc[s] = c;
    ws[s] = sn;
}

// Kernel 2: one block per batch row. Two 16384-length dot products with the
// precomputed weight tables (L2-resident), then the scalar epilogue.
__global__ __launch_bounds__(256) void welch_dot_kernel(
        const float* __restrict__ inp,
        const float* __restrict__ wc,
        const float* __restrict__ ws,
        const float* __restrict__ fc_w,
        const float* __restrict__ fc_b,
        float* __restrict__ out) {
    const int row = blockIdx.x;
    const int t   = threadIdx.x;

    const float4* __restrict__ x4  = (const float4*)(inp + (size_t)row * SEQ);
    const float4* __restrict__ wc4 = (const float4*)wc;
    const float4* __restrict__ ws4 = (const float4*)ws;

    float sr = 0.f, si = 0.f;
    #pragma unroll
    for (int i = 0; i < SEQ / 4 / 256; ++i) {   // 16 float4s per thread
        int j = t + i * 256;                     // coalesced: lane-contiguous
        float4 xv = x4[j];
        float4 cv = wc4[j];
        float4 sv = ws4[j];
        sr += xv.x * cv.x + xv.y * cv.y + xv.z * cv.z + xv.w * cv.w;
        si += xv.x * sv.x + xv.y * sv.y + xv.z * sv.z + xv.w * sv.w;
    }

    // wave64 butterfly reduce
    #pragma unroll
    for (int off = 32; off > 0; off >>= 1) {
        sr += __shfl_down(sr, off, 64);
        si += __shfl_down(si, off, 64);
    }

    __shared__ float red[8];
    int wave = t >> 6;
    int lane = t & 63;
    if (lane == 0) { red[wave * 2] = sr; red[wave * 2 + 1] = si; }
    __syncthreads();

    if (t == 0) {
        float fr = 0.f, fi = 0.f;
        #pragma unroll
        for (int w = 0; w < 4; ++w) { fr += red[w * 2]; fi += red[w * 2 + 1]; }
        fr *= (1.0f / NWIN);
        fi *= (1.0f / NWIN);
        out[row] = (fr * fr + fi * fi) * fc_w[0] + fc_b[0];
    }
}

extern "C" void kernel_launch(void* const* d_in, const int* in_sizes, int n_in,
                              void* d_out, int out_size, void* d_ws, size_t ws_size,
                              hipStream_t stream) {
    const float* inp   = (const float*)d_in[0];   // (1024, 16384) f32
    const float* freqs = (const float*)d_in[1];   // (1024,) f32
    const float* fc_w  = (const float*)d_in[2];   // (1,1) f32
    const float* fc_b  = (const float*)d_in[3];   // (1,) f32
    float* out = (float*)d_out;                   // (1024, 1) f32

    float* wc = (float*)d_ws;                     // 16384 floats
    float* ws = wc + SEQ;                         // 16384 floats (128 KiB total)

    welch_weights_kernel<<<SEQ / 256, 256, 0, stream>>>(freqs, wc, ws);
    welch_dot_kernel<<<BATCH, 256, 0, stream>>>(inp, wc, ws, fc_w, fc_b, out);
}